// Round 16
// baseline (290.158 us; speedup 1.0000x reference)
//
#include <hip/hip_runtime.h>
#include <hip/hip_bf16.h>
#include <cstdint>

#define DI __device__ __forceinline__

typedef __attribute__((ext_vector_type(4))) float f32x4;
typedef __attribute__((ext_vector_type(16))) float f32x16;
typedef __attribute__((ext_vector_type(8))) short s16x8;
typedef __attribute__((ext_vector_type(4))) short s16x4;
typedef __attribute__((ext_vector_type(4))) unsigned int u32x4;
typedef unsigned int u32;

constexpr int Sc = 2048;
constexpr float LOG2E = 1.44269504088896340736f;
// B=4, D=1024, H=16, DK=64, M = B*S = 8192, BH = 64

DI short f2bf(float x) {
    __hip_bfloat16 h = __float2bfloat16(x);
    return __builtin_bit_cast(short, h);
}
DI float bf2f(short x) {
    __hip_bfloat16 h = __builtin_bit_cast(__hip_bfloat16, x);
    return __bfloat162float(h);
}
DI u32 pack2(float a, float b) {
    return (u32)(unsigned short)f2bf(a) | ((u32)(unsigned short)f2bf(b) << 16);
}
// swap rows: a' = [a.row0, b.row0]; b' = [a.row1, b.row1]  (rows = 32-lane halves)
DI void pl32swap(u32& a, u32& b) {
    asm("v_permlane32_swap_b32 %0, %1" : "+v"(a), "+v"(b));
}

// async 16B global -> LDS (dest = wave-uniform base + lane*16)
DI void cp16(const short* g, short* l) {
    __builtin_amdgcn_global_load_lds(
        (const __attribute__((address_space(1))) u32*)g,
        (__attribute__((address_space(3))) u32*)l, 16, 0, 0);
}

DI float fexp2(float x) {
#if __has_builtin(__builtin_amdgcn_exp2f)
    return __builtin_amdgcn_exp2f(x);
#else
    return exp2f(x);
#endif
}
DI float frcp(float x) {
#if __has_builtin(__builtin_amdgcn_rcpf)
    return __builtin_amdgcn_rcpf(x);
#else
    return 1.0f / x;
#endif
}

// ---- Merged prep: blocks [0,8192) xconv; [8192,12288) wconv (z = (b-8192)>>10);
//      [12288,12544) bias table. All paths identical math to r15's separate kernels.
__global__ void prep_kernel(const float* __restrict__ X,
                            const float* __restrict__ Wq, const float* __restrict__ Wk,
                            const float* __restrict__ Wv, const float* __restrict__ Wo,
                            const float* __restrict__ RB,
                            short* __restrict__ X2, short* __restrict__ WT2,
                            short* __restrict__ WoT, short* __restrict__ btab) {
    __shared__ float t[32][33];
    const int b = blockIdx.x;
    const int tid = threadIdx.x;
    if (b < 8192) {
        // X [8192][1024] f32 -> X2h bf16 (hi only)
        size_t i = ((size_t)b * 256 + tid) * 4;
        float4 v = *reinterpret_cast<const float4*>(X + i);
        s16x4 h4 = {f2bf(v.x), f2bf(v.y), f2bf(v.z), f2bf(v.w)};
        *reinterpret_cast<s16x4*>(X2 + i) = h4;
    } else if (b < 12288) {
        const int zb = b - 8192;
        const int z = zb >> 10;
        const int rem = zb & 1023;
        const int k0 = (rem >> 5) * 32, n0 = (rem & 31) * 32;
        const int tx = tid & 31, ty = tid >> 5;
        const float* W = (z == 0) ? Wq : (z == 1 ? Wk : (z == 2 ? Wv : Wo));
#pragma unroll
        for (int i = 0; i < 4; ++i)
            t[ty + 8 * i][tx] = W[(size_t)(k0 + ty + 8 * i) * 1024 + n0 + tx];
        __syncthreads();
        if (z < 3) {
#pragma unroll
            for (int i = 0; i < 4; ++i) {
                float v = t[tx][ty + 8 * i];
                short hi = f2bf(v), lo = f2bf(v - bf2f(hi));
                size_t r = (size_t)(z * 1024 + n0 + ty + 8 * i) * 2048 + k0 + tx;
                WT2[r] = hi;
                WT2[r + 1024] = lo;
            }
        } else {
#pragma unroll
            for (int i = 0; i < 4; ++i)
                WoT[(size_t)(n0 + ty + 8 * i) * 1024 + k0 + tx] = f2bf(t[tx][ty + 8 * i]);
        }
    } else {
        // bias table [16][4096] bf16, pre-scaled by log2(e); exact integer bucket thresholds
        int idx = (b - 12288) * 256 + tid;
        int h = idx >> 12;
        int i = idx & 4095;
        int delta = i - 2047;
        int ad = delta < 0 ? -delta : delta;
        int bk;
        if (ad < 8) bk = ad;
        else if (ad < 12) bk = 8;
        else if (ad < 16) bk = 9;
        else if (ad < 23) bk = 10;
        else if (ad < 32) bk = 11;
        else if (ad < 46) bk = 12;
        else if (ad < 64) bk = 13;
        else if (ad < 91) bk = 14;
        else bk = 15;
        if (delta > 0) bk += 16;
        btab[idx] = f2bf(RB[bk * 16 + h] * LOG2E);
    }
}

// ---- GEMM (m97 2-barrier structure, BK=64 + XOR-swizzled LDS; validated r13/r14/r15).
// r16: 1D grid + bijective XCD swizzle -- each XCD owns contiguous m-blocks of a B-panel
// (same-y blocks co-located -> B panel stays in that XCD's L2). Arithmetic unchanged.
// Grid = 64*NY blocks; decode: sw = (bid&7)*(grid/8) + (bid>>3); m0 = (sw&63)*128; y = sw>>6.
// EPI=0: fp32 C.
// EPI=1 (fused QKV): region = y>>3. Q: 32 iters (XhWh+XhWl), hi|lo 128-wide out.
//   K: 16 iters (XhWh), hi-only 64-wide out. V: 16 iters (XhWh), V^T bf16 out.
template <int EPI>
__launch_bounds__(256)
__global__ void gemm_bt(const short* __restrict__ A, const short* __restrict__ Bt,
                        int K, int lda, int ldb, int aWrap, int bWrap,
                        float* __restrict__ C, int ldc,
                        short* __restrict__ q2, short* __restrict__ k2, short* __restrict__ vt) {
    __shared__ __align__(16) short As[128 * 64];
    __shared__ __align__(16) short Bs[128 * 64];
    const int tid = threadIdx.x;
    const int w = tid >> 6, l = tid & 63;
    const int bid = blockIdx.x;
    const int sw = (bid & 7) * ((int)gridDim.x >> 3) + (bid >> 3);
    const int m0 = (sw & 63) * 128;
    const int yb = sw >> 6;
    const int n0 = yb * 128;
    const int wm = (w >> 1) * 64, wn = (w & 1) * 64;
    const int rl = l >> 4, cl = l & 15;

    const int region = (EPI == 1) ? (yb >> 3) : 0;  // 0=Q 1=K 2=V (block-uniform)

    f32x4 acc[4][4];
#pragma unroll
    for (int i = 0; i < 4; ++i)
#pragma unroll
        for (int j = 0; j < 4; ++j) acc[i][j] = (f32x4){0.f, 0.f, 0.f, 0.f};

    const int nk = K / 64;
    const int nkUse = (EPI == 1) ? (region == 0 ? 32 : 16) : nk;

    const int o0 = w * 64 + l;
    const int sr0 = o0 >> 3;
    const int scg = (o0 & 7) ^ (sr0 & 7);
    const int swz = cl & 7;

    for (int kt = 0; kt < nkUse; ++kt) {
        int kk = kt * 64;
        int ca = kk - (kk >= aWrap ? aWrap : 0);
        int cb = kk - (kk >= bWrap ? bWrap : 0);
#pragma unroll
        for (int j = 0; j < 4; ++j) {
            int r = j * 32 + sr0;
            cp16(A + (size_t)(m0 + r) * lda + ca + scg * 8, As + (j * 256 + w * 64) * 8);
            cp16(Bt + (size_t)(n0 + r) * ldb + cb + scg * 8, Bs + (j * 256 + w * 64) * 8);
        }
        __syncthreads();
#pragma unroll
        for (int ks = 0; ks < 2; ++ks) {
            const int slot = ((ks << 2) | rl) ^ swz;
            s16x8 af[4], bfv[4];
#pragma unroll
            for (int i = 0; i < 4; ++i)
                af[i] = *reinterpret_cast<const s16x8*>(As + (wm + i * 16 + cl) * 64 + slot * 8);
#pragma unroll
            for (int i = 0; i < 4; ++i)
                bfv[i] = *reinterpret_cast<const s16x8*>(Bs + (wn + i * 16 + cl) * 64 + slot * 8);
#pragma unroll
            for (int mi = 0; mi < 4; ++mi)
#pragma unroll
                for (int ni = 0; ni < 4; ++ni)
                    acc[mi][ni] = __builtin_amdgcn_mfma_f32_16x16x32_bf16(af[mi], bfv[ni], acc[mi][ni], 0, 0, 0);
        }
        __syncthreads();
    }

    if (EPI == 0) {
#pragma unroll
        for (int mi = 0; mi < 4; ++mi) {
            int row = m0 + wm + mi * 16 + rl * 4;
#pragma unroll
            for (int ni = 0; ni < 4; ++ni) {
                int col = n0 + wn + ni * 16 + cl;
#pragma unroll
                for (int r = 0; r < 4; ++r)
                    C[(size_t)(row + r) * ldc + col] = acc[mi][ni][r];
            }
        }
    } else {
#pragma unroll
        for (int mi = 0; mi < 4; ++mi) {
#pragma unroll
            for (int ni = 0; ni < 4; ++ni) {
#pragma unroll
                for (int r = 0; r < 4; ++r) {
                    int m = m0 + wm + mi * 16 + rl * 4 + r;
                    int n = (n0 & 1023) + wn + ni * 16 + cl;
                    int bb = m >> 11, s = m & 2047;
                    int h = n >> 6, d = n & 63;
                    int bh = bb * 16 + h;
                    float c = acc[mi][ni][r];
                    if (region == 0) {
                        c *= LOG2E;  // fold softmax base-2 conversion into Q
                        short hi = f2bf(c);
                        short lo = f2bf(c - bf2f(hi));
                        size_t base = ((size_t)bh * 2048 + s) * 128;
                        q2[base + d] = hi;
                        q2[base + 64 + d] = lo;
                    } else if (region == 1) {
                        k2[((size_t)bh * 2048 + s) * 64 + d] = f2bf(c);
                    } else {
                        vt[((size_t)bh * 64 + d) * 2048 + s] = f2bf(c);
                    }
                }
            }
        }
    }
}

// ---- Flash attention, 32x32 swapped-operand form (validated r5/r8/r10/r12/r13/r14/r15).
// Grid: 512 blocks (XCD-swizzled), 512 threads = 8 waves; wave owns 32 q-rows (q-block 256).
// Swapped QK: mfma(A=Kh, B=Q') -> lane holds 16 scores of ONE q-row (q = lane&31).
// K hi-only (64-wide) -> 8 QK MFMAs (Kh.Qh + Kh.Ql).
// FAR-TILE BIAS SHORTCUT: bucket constant for |delta|>=91; wave-uniform far test skips
// all bias LDS reads for ~87% of subtiles (bit-identical value).
// P stays in registers; cross-half exchange via v_permlane32_swap_b32 (VALU).
// Near tiles: bias pairs read as ONE aligned ds_read_b32 via dual-parity Bsh0/Bsh1.
// Index bound: i0 = kvg - qL + 255 <= 2301; Bsh0 fill 2304, Bsh1 fill 2302.
// No online max (|score*log2e| < ~90 << 127, exp2/fp32-sum safe); psum is in-lane scalar.
__launch_bounds__(512, 4)
__global__ void flash_kernel(const short* __restrict__ q2, const short* __restrict__ k2,
                             const short* __restrict__ vt, const short* __restrict__ btab,
                             short* __restrict__ attnb) {
    __shared__ __align__(16) short Ks[2][4096];   // [buf] 64 rows x 8 chunks(16B), slot = c ^ (r&7)
    __shared__ __align__(16) short Vs[2][4096];   // [buf] 64 d-rows x 8 chunks, slot = c ^ (d&7)
    __shared__ __align__(16) short Bsh0[2304];    // bias slice (bf16, log2e-scaled)
    __shared__ __align__(16) short Bsh1[2304];    // same shifted by +1 (odd-parity pair reads)

    const int tid = threadIdx.x;
    const int w = tid >> 6, l = tid & 63;
    const int l31 = l & 31, hi = l >> 5;

    const int L = blockIdx.x;
    const int xcd = L & 7, idx = L >> 3;
    const int bh = xcd + 8 * (idx & 7);
    const int qb = idx >> 3;
    const int h = bh & 15;
    const int q0b = qb * 256;
    const int qw0 = q0b + w * 32;     // global first q-row of this wave
    const int qL = w * 32 + l31;      // block-local q row

    const short* Q = q2 + (size_t)bh * Sc * 128;
    const short* Kp = k2 + (size_t)bh * Sc * 64;   // 64-wide hi-only
    const short* V = vt + (size_t)bh * 64 * Sc;

    // far-bias constants (exact table entries for |delta| >= 91)
    const float bneg = bf2f(btab[h * 4096 + 2047 - 91]);
    const float bpos = bf2f(btab[h * 4096 + 2047 + 91]);

    {
        int base = h * 4096 + 1792 - q0b;
        for (int i = tid; i < 2304; i += 512) Bsh0[i] = btab[base + i];
        for (int i = tid; i < 2302; i += 512) Bsh1[i] = btab[base + i + 1];
    }

    auto stage = [&](int buf, int it2) {
        int kv0 = it2 * 64;
        {
            int o = w * 64 + l;                    // K chunk index 0..511
            int r = o >> 3, cs = o & 7;
            int cg = cs ^ (r & 7);
            cp16(Kp + (size_t)(kv0 + r) * 64 + cg * 8, &Ks[buf][(w * 64) * 8]);
        }
        {
            int o = w * 64 + l;                    // V chunk index 0..511
            int d = o >> 3, cs = o & 7;
            int cg = cs ^ (d & 7);
            cp16(V + (size_t)d * 2048 + kv0 + cg * 8, &Vs[buf][(w * 64) * 8]);
        }
    };

    s16x8 qf[8];
#pragma unroll
    for (int c = 0; c < 8; ++c)
        qf[c] = *reinterpret_cast<const s16x8*>(Q + (size_t)(qw0 + l31) * 128 + c * 16 + hi * 8);

    f32x16 accO[2];
#pragma unroll
    for (int i = 0; i < 16; ++i) { accO[0][i] = 0.f; accO[1][i] = 0.f; }
    float psum = 0.f;

    stage(0, 0);
    __syncthreads();

    for (int it = 0; it < 32; ++it) {
        const int cur = it & 1;
        if (it + 1 < 32) stage(cur ^ 1, it + 1);
        const int kv0 = it * 64;
#pragma unroll
        for (int T = 0; T < 2; ++T) {
            const int rA = T * 32 + l31;
            const int rsw = rA & 7;
            const short* kbase = &Ks[cur][rA * 64];
            s16x8 kh[4];
#pragma unroll
            for (int c = 0; c < 4; ++c)
                kh[c] = *reinterpret_cast<const s16x8*>(kbase + ((c * 2 + hi) ^ rsw) * 8);
            f32x16 acc = {0.f,0.f,0.f,0.f,0.f,0.f,0.f,0.f,0.f,0.f,0.f,0.f,0.f,0.f,0.f,0.f};
#pragma unroll
            for (int c = 0; c < 4; ++c)  // Kh . Qh
                acc = __builtin_amdgcn_mfma_f32_32x32x16_bf16(kh[c], qf[c], acc, 0, 0, 0);
#pragma unroll
            for (int c = 0; c < 4; ++c)  // Kh . Ql
                acc = __builtin_amdgcn_mfma_f32_32x32x16_bf16(kh[c], qf[c + 4], acc, 0, 0, 0);

            // wave-uniform far test for this 32-kv subtile vs this wave's 32 q-rows
            const int kvT0 = kv0 + T * 32;
            const int dmax = kvT0 + 31 - qw0;   // max delta over (lane, elem)
            const int dmin = kvT0 - qw0 - 31;   // min delta
            const bool faru = (dmax <= -91) || (dmin >= 91);
            const float bunif = (dmax <= -91) ? bneg : bpos;

            auto softpv = [&](bool far) {
#pragma unroll
                for (int t2 = 0; t2 < 2; ++t2) {
                    u32 pk[4];
#pragma unroll
                    for (int i = 0; i < 4; ++i) {
                        const int ii = t2 * 4 + i;
                        const int pstart = ((ii & 1) * 2) + ((ii >> 1) * 8);
                        float b0, b1;
                        if (far) {
                            b0 = bunif; b1 = bunif;
                        } else {
                            const int kvg = kv0 + T * 32 + pstart + 4 * hi;  // even
                            const int i0 = kvg - qL + 255;
                            const short* bp = (i0 & 1) ? (Bsh1 + (i0 - 1)) : (Bsh0 + i0);
                            const u32 pr2 = *reinterpret_cast<const u32*>(bp);  // 4B-aligned
                            b0 = bf2f((short)(pr2 & 0xffff));
                            b1 = bf2f((short)(pr2 >> 16));
                        }
                        const int r0 = t2 * 8 + i * 2;
                        const float e0 = fexp2(acc[r0] + b0);
                        const float e1 = fexp2(acc[r0 + 1] + b1);
                        psum += e0 + e1;
                        pk[i] = pack2(e0, e1);
                    }
                    pl32swap(pk[0], pk[2]);
                    pl32swap(pk[1], pk[3]);
                    u32x4 pv4 = {pk[0], pk[1], pk[2], pk[3]};
                    s16x8 pfrag = __builtin_bit_cast(s16x8, pv4);
                    const int tg = T * 2 + t2;
#pragma unroll
                    for (int dt = 0; dt < 2; ++dt) {
                        const int d = dt * 32 + l31;
                        s16x8 vf = *reinterpret_cast<const s16x8*>(
                            &Vs[cur][d * 64 + ((tg * 2 + hi) ^ (d & 7)) * 8]);
                        accO[dt] = __builtin_amdgcn_mfma_f32_32x32x16_bf16(pfrag, vf, accO[dt], 0, 0, 0);
                    }
                }
            };
            if (faru) softpv(true);   // wave-uniform branch: skips all bias LDS reads
            else      softpv(false);
        }
        __syncthreads();
    }

    psum += __shfl_xor(psum, 32);

    const int bb = bh >> 4;
#pragma unroll
    for (int r = 0; r < 16; ++r) {
        const int qloc = (r & 3) + 8 * (r >> 2) + 4 * hi;
        const float inv = frcp(__shfl(psum, qloc));
        const size_t rowbase = ((size_t)(bb * 2048 + qw0 + qloc)) * 1024 + h * 64;
#pragma unroll
        for (int dt = 0; dt < 2; ++dt)
            attnb[rowbase + dt * 32 + l31] = f2bf(accO[dt][r] * inv);
    }
}

extern "C" void kernel_launch(void* const* d_in, const int* in_sizes, int n_in,
                              void* d_out, int out_size, void* d_ws, size_t ws_size,
                              hipStream_t stream) {
    const float* X = (const float*)d_in[0];
    const float* Wq = (const float*)d_in[1];
    const float* Wk = (const float*)d_in[2];
    const float* Wv = (const float*)d_in[3];
    const float* Wo = (const float*)d_in[4];
    const float* RB = (const float*)d_in[5];

    char* ws = (char*)d_ws;
    size_t off = 0;
    auto alloc = [&](size_t bytes) {
        void* p = ws + off;
        off += (bytes + 255) & ~(size_t)255;
        return p;
    };
    short* X2 = (short*)alloc((size_t)8192 * 1024 * 2);      // X hi only
    short* WT2 = (short*)alloc((size_t)3072 * 2048 * 2);
    short* q2 = (short*)alloc((size_t)64 * 2048 * 128 * 2);
    short* k2 = (short*)alloc((size_t)64 * 2048 * 64 * 2);   // hi-only, 64-wide
    short* vt = (short*)alloc((size_t)64 * 64 * 2048 * 2);
    short* attn = (short*)alloc((size_t)8192 * 1024 * 2);
    short* WoT = (short*)alloc((size_t)1024 * 1024 * 2);
    short* btab = (short*)alloc((size_t)16 * 4096 * 2);

    // merged prep: xconv (8192 blocks) + wconv (4096) + bias (256)
    prep_kernel<<<12544, 256, 0, stream>>>(X, Wq, Wk, Wv, Wo, RB, X2, WT2, WoT, btab);
    // Fused QKV projection (1536 blocks, 1D + XCD swizzle), BK=64:
    // Q 32 iters (2-term), K 16 iters (1-term), V 16 iters.
    gemm_bt<1><<<1536, 256, 0, stream>>>(X2, WT2, 3072, 1024, 2048, 1024, 2048,
                                         nullptr, 0, q2, k2, vt);
    flash_kernel<<<512, 512, 0, stream>>>(q2, k2, vt, btab, attn);
    // Output projection (single bf16), K=1024 -> 16 iters (512 blocks, 1D + XCD swizzle)
    gemm_bt<0><<<512, 256, 0, stream>>>(attn, WoT, 1024, 1024, 1024, 1 << 30, 1 << 30,
                                        (float*)d_out, 1024, nullptr, nullptr, nullptr);
}

// Round 17
// 248.527 us; speedup vs baseline: 1.1675x; 1.1675x over previous
//
#include <hip/hip_runtime.h>
#include <hip/hip_bf16.h>
#include <cstdint>

#define DI __device__ __forceinline__

typedef __attribute__((ext_vector_type(4))) float f32x4;
typedef __attribute__((ext_vector_type(16))) float f32x16;
typedef __attribute__((ext_vector_type(8))) short s16x8;
typedef __attribute__((ext_vector_type(4))) short s16x4;
typedef __attribute__((ext_vector_type(4))) unsigned int u32x4;
typedef unsigned int u32;

constexpr int Sc = 2048;
constexpr float LOG2E = 1.44269504088896340736f;
// B=4, D=1024, H=16, DK=64, M = B*S = 8192, BH = 64

DI short f2bf(float x) {
    __hip_bfloat16 h = __float2bfloat16(x);
    return __builtin_bit_cast(short, h);
}
DI float bf2f(short x) {
    __hip_bfloat16 h = __builtin_bit_cast(__hip_bfloat16, x);
    return __bfloat162float(h);
}
DI u32 pack2(float a, float b) {
    return (u32)(unsigned short)f2bf(a) | ((u32)(unsigned short)f2bf(b) << 16);
}
// swap rows: a' = [a.row0, b.row0]; b' = [a.row1, b.row1]  (rows = 32-lane halves)
DI void pl32swap(u32& a, u32& b) {
    asm("v_permlane32_swap_b32 %0, %1" : "+v"(a), "+v"(b));
}

// async 16B global -> LDS (dest = wave-uniform base + lane*16)
DI void cp16(const short* g, short* l) {
    __builtin_amdgcn_global_load_lds(
        (const __attribute__((address_space(1))) u32*)g,
        (__attribute__((address_space(3))) u32*)l, 16, 0, 0);
}

DI float fexp2(float x) {
#if __has_builtin(__builtin_amdgcn_exp2f)
    return __builtin_amdgcn_exp2f(x);
#else
    return exp2f(x);
#endif
}
DI float frcp(float x) {
#if __has_builtin(__builtin_amdgcn_rcpf)
    return __builtin_amdgcn_rcpf(x);
#else
    return 1.0f / x;
#endif
}

// ---- Merged prep: blocks [0,8192) xconv; [8192,12288) wconv (z = (b-8192)>>10);
//      [12288,12544) bias table. All paths identical math to r15's separate kernels.
__global__ void prep_kernel(const float* __restrict__ X,
                            const float* __restrict__ Wq, const float* __restrict__ Wk,
                            const float* __restrict__ Wv, const float* __restrict__ Wo,
                            const float* __restrict__ RB,
                            short* __restrict__ X2, short* __restrict__ WT2,
                            short* __restrict__ WoT, short* __restrict__ btab) {
    __shared__ float t[32][33];
    const int b = blockIdx.x;
    const int tid = threadIdx.x;
    if (b < 8192) {
        // X [8192][1024] f32 -> X2h bf16 (hi only)
        size_t i = ((size_t)b * 256 + tid) * 4;
        float4 v = *reinterpret_cast<const float4*>(X + i);
        s16x4 h4 = {f2bf(v.x), f2bf(v.y), f2bf(v.z), f2bf(v.w)};
        *reinterpret_cast<s16x4*>(X2 + i) = h4;
    } else if (b < 12288) {
        const int zb = b - 8192;
        const int z = zb >> 10;
        const int rem = zb & 1023;
        const int k0 = (rem >> 5) * 32, n0 = (rem & 31) * 32;
        const int tx = tid & 31, ty = tid >> 5;
        const float* W = (z == 0) ? Wq : (z == 1 ? Wk : (z == 2 ? Wv : Wo));
#pragma unroll
        for (int i = 0; i < 4; ++i)
            t[ty + 8 * i][tx] = W[(size_t)(k0 + ty + 8 * i) * 1024 + n0 + tx];
        __syncthreads();
        if (z < 3) {
#pragma unroll
            for (int i = 0; i < 4; ++i) {
                float v = t[tx][ty + 8 * i];
                short hi = f2bf(v), lo = f2bf(v - bf2f(hi));
                size_t r = (size_t)(z * 1024 + n0 + ty + 8 * i) * 2048 + k0 + tx;
                WT2[r] = hi;
                WT2[r + 1024] = lo;
            }
        } else {
#pragma unroll
            for (int i = 0; i < 4; ++i)
                WoT[(size_t)(n0 + ty + 8 * i) * 1024 + k0 + tx] = f2bf(t[tx][ty + 8 * i]);
        }
    } else {
        // bias table [16][4096] bf16, pre-scaled by log2(e); exact integer bucket thresholds
        int idx = (b - 12288) * 256 + tid;
        int h = idx >> 12;
        int i = idx & 4095;
        int delta = i - 2047;
        int ad = delta < 0 ? -delta : delta;
        int bk;
        if (ad < 8) bk = ad;
        else if (ad < 12) bk = 8;
        else if (ad < 16) bk = 9;
        else if (ad < 23) bk = 10;
        else if (ad < 32) bk = 11;
        else if (ad < 46) bk = 12;
        else if (ad < 64) bk = 13;
        else if (ad < 91) bk = 14;
        else bk = 15;
        if (delta > 0) bk += 16;
        btab[idx] = f2bf(RB[bk * 16 + h] * LOG2E);
    }
}

// ---- GEMM (m97 2-barrier structure, BK=64 + XOR-swizzled LDS; validated r13/r14/r15).
// 2D grid, default block mapping (r17: reverted r16's XCD swizzle -- the default x-fast
// round-robin puts m%8 -> XCD, giving each XCD a fixed 2MB A-slice that L2-caches across
// all B-panels; FETCH 58MB vs 266MB with the "smart" swizzle).
// C[M,N] = A[M,K'] * B[K',N], B given as B^T [N][K'].
// Staging: pre-swizzled GLOBAL source + linear LDS dest; slot = chunk ^ (row&7).
// Split-K' remap: col = kk - (kk>=wrap ? wrap : 0).
// EPI=0: fp32 C.
// EPI=1 (fused QKV): region = n0>>10.
//   Q: 32 iters (XhWh + XhWl), hi|lo 128-wide out.
//   K: 16 iters (XhWh), hi-only 64-wide out.
//   V: 16 iters (XhWh), V^T bf16 out.
template <int EPI>
__launch_bounds__(256)
__global__ void gemm_bt(const short* __restrict__ A, const short* __restrict__ Bt,
                        int K, int lda, int ldb, int aWrap, int bWrap,
                        float* __restrict__ C, int ldc,
                        short* __restrict__ q2, short* __restrict__ k2, short* __restrict__ vt) {
    __shared__ __align__(16) short As[128 * 64];
    __shared__ __align__(16) short Bs[128 * 64];
    const int tid = threadIdx.x;
    const int w = tid >> 6, l = tid & 63;
    const int m0 = blockIdx.x * 128, n0 = blockIdx.y * 128;
    const int wm = (w >> 1) * 64, wn = (w & 1) * 64;
    const int rl = l >> 4, cl = l & 15;

    const int region = (EPI == 1) ? (n0 >> 10) : 0;  // 0=Q 1=K 2=V (block-uniform)

    f32x4 acc[4][4];
#pragma unroll
    for (int i = 0; i < 4; ++i)
#pragma unroll
        for (int j = 0; j < 4; ++j) acc[i][j] = (f32x4){0.f, 0.f, 0.f, 0.f};

    const int nk = K / 64;
    const int nkUse = (EPI == 1) ? (region == 0 ? 32 : 16) : nk;

    const int o0 = w * 64 + l;
    const int sr0 = o0 >> 3;
    const int scg = (o0 & 7) ^ (sr0 & 7);
    const int sw = cl & 7;

    for (int kt = 0; kt < nkUse; ++kt) {
        int kk = kt * 64;
        int ca = kk - (kk >= aWrap ? aWrap : 0);
        int cb = kk - (kk >= bWrap ? bWrap : 0);
#pragma unroll
        for (int j = 0; j < 4; ++j) {
            int r = j * 32 + sr0;
            cp16(A + (size_t)(m0 + r) * lda + ca + scg * 8, As + (j * 256 + w * 64) * 8);
            cp16(Bt + (size_t)(n0 + r) * ldb + cb + scg * 8, Bs + (j * 256 + w * 64) * 8);
        }
        __syncthreads();
#pragma unroll
        for (int ks = 0; ks < 2; ++ks) {
            const int slot = ((ks << 2) | rl) ^ sw;
            s16x8 af[4], bfv[4];
#pragma unroll
            for (int i = 0; i < 4; ++i)
                af[i] = *reinterpret_cast<const s16x8*>(As + (wm + i * 16 + cl) * 64 + slot * 8);
#pragma unroll
            for (int i = 0; i < 4; ++i)
                bfv[i] = *reinterpret_cast<const s16x8*>(Bs + (wn + i * 16 + cl) * 64 + slot * 8);
#pragma unroll
            for (int mi = 0; mi < 4; ++mi)
#pragma unroll
                for (int ni = 0; ni < 4; ++ni)
                    acc[mi][ni] = __builtin_amdgcn_mfma_f32_16x16x32_bf16(af[mi], bfv[ni], acc[mi][ni], 0, 0, 0);
        }
        __syncthreads();
    }

    if (EPI == 0) {
#pragma unroll
        for (int mi = 0; mi < 4; ++mi) {
            int row = m0 + wm + mi * 16 + rl * 4;
#pragma unroll
            for (int ni = 0; ni < 4; ++ni) {
                int col = n0 + wn + ni * 16 + cl;
#pragma unroll
                for (int r = 0; r < 4; ++r)
                    C[(size_t)(row + r) * ldc + col] = acc[mi][ni][r];
            }
        }
    } else {
#pragma unroll
        for (int mi = 0; mi < 4; ++mi) {
#pragma unroll
            for (int ni = 0; ni < 4; ++ni) {
#pragma unroll
                for (int r = 0; r < 4; ++r) {
                    int m = m0 + wm + mi * 16 + rl * 4 + r;
                    int n = (n0 & 1023) + wn + ni * 16 + cl;
                    int bb = m >> 11, s = m & 2047;
                    int h = n >> 6, d = n & 63;
                    int bh = bb * 16 + h;
                    float c = acc[mi][ni][r];
                    if (region == 0) {
                        c *= LOG2E;  // fold softmax base-2 conversion into Q
                        short hi = f2bf(c);
                        short lo = f2bf(c - bf2f(hi));
                        size_t base = ((size_t)bh * 2048 + s) * 128;
                        q2[base + d] = hi;
                        q2[base + 64 + d] = lo;
                    } else if (region == 1) {
                        k2[((size_t)bh * 2048 + s) * 64 + d] = f2bf(c);
                    } else {
                        vt[((size_t)bh * 64 + d) * 2048 + s] = f2bf(c);
                    }
                }
            }
        }
    }
}

// ---- Flash attention, 32x32 swapped-operand form (validated r5/r8/r10/r12/r13/r14/r15).
// Grid: 512 blocks (XCD-swizzled), 512 threads = 8 waves; wave owns 32 q-rows (q-block 256).
// Swapped QK: mfma(A=Kh, B=Q') -> lane holds 16 scores of ONE q-row (q = lane&31).
// K hi-only (64-wide) -> 8 QK MFMAs (Kh.Qh + Kh.Ql).
// FAR-TILE BIAS SHORTCUT: bucket constant for |delta|>=91; wave-uniform far test skips
// all bias LDS reads for ~87% of subtiles (bit-identical value).
// P stays in registers; cross-half exchange via v_permlane32_swap_b32 (VALU).
// Near tiles: bias pairs read as ONE aligned ds_read_b32 via dual-parity Bsh0/Bsh1.
// Index bound: i0 = kvg - qL + 255 <= 2301; Bsh0 fill 2304, Bsh1 fill 2302.
// No online max (|score*log2e| < ~90 << 127, exp2/fp32-sum safe); psum is in-lane scalar.
__launch_bounds__(512, 4)
__global__ void flash_kernel(const short* __restrict__ q2, const short* __restrict__ k2,
                             const short* __restrict__ vt, const short* __restrict__ btab,
                             short* __restrict__ attnb) {
    __shared__ __align__(16) short Ks[2][4096];   // [buf] 64 rows x 8 chunks(16B), slot = c ^ (r&7)
    __shared__ __align__(16) short Vs[2][4096];   // [buf] 64 d-rows x 8 chunks, slot = c ^ (d&7)
    __shared__ __align__(16) short Bsh0[2304];    // bias slice (bf16, log2e-scaled)
    __shared__ __align__(16) short Bsh1[2304];    // same shifted by +1 (odd-parity pair reads)

    const int tid = threadIdx.x;
    const int w = tid >> 6, l = tid & 63;
    const int l31 = l & 31, hi = l >> 5;

    const int L = blockIdx.x;
    const int xcd = L & 7, idx = L >> 3;
    const int bh = xcd + 8 * (idx & 7);
    const int qb = idx >> 3;
    const int h = bh & 15;
    const int q0b = qb * 256;
    const int qw0 = q0b + w * 32;     // global first q-row of this wave
    const int qL = w * 32 + l31;      // block-local q row

    const short* Q = q2 + (size_t)bh * Sc * 128;
    const short* Kp = k2 + (size_t)bh * Sc * 64;   // 64-wide hi-only
    const short* V = vt + (size_t)bh * 64 * Sc;

    // far-bias constants (exact table entries for |delta| >= 91)
    const float bneg = bf2f(btab[h * 4096 + 2047 - 91]);
    const float bpos = bf2f(btab[h * 4096 + 2047 + 91]);

    {
        int base = h * 4096 + 1792 - q0b;
        for (int i = tid; i < 2304; i += 512) Bsh0[i] = btab[base + i];
        for (int i = tid; i < 2302; i += 512) Bsh1[i] = btab[base + i + 1];
    }

    auto stage = [&](int buf, int it2) {
        int kv0 = it2 * 64;
        {
            int o = w * 64 + l;                    // K chunk index 0..511
            int r = o >> 3, cs = o & 7;
            int cg = cs ^ (r & 7);
            cp16(Kp + (size_t)(kv0 + r) * 64 + cg * 8, &Ks[buf][(w * 64) * 8]);
        }
        {
            int o = w * 64 + l;                    // V chunk index 0..511
            int d = o >> 3, cs = o & 7;
            int cg = cs ^ (d & 7);
            cp16(V + (size_t)d * 2048 + kv0 + cg * 8, &Vs[buf][(w * 64) * 8]);
        }
    };

    s16x8 qf[8];
#pragma unroll
    for (int c = 0; c < 8; ++c)
        qf[c] = *reinterpret_cast<const s16x8*>(Q + (size_t)(qw0 + l31) * 128 + c * 16 + hi * 8);

    f32x16 accO[2];
#pragma unroll
    for (int i = 0; i < 16; ++i) { accO[0][i] = 0.f; accO[1][i] = 0.f; }
    float psum = 0.f;

    stage(0, 0);
    __syncthreads();

    for (int it = 0; it < 32; ++it) {
        const int cur = it & 1;
        if (it + 1 < 32) stage(cur ^ 1, it + 1);
        const int kv0 = it * 64;
#pragma unroll
        for (int T = 0; T < 2; ++T) {
            const int rA = T * 32 + l31;
            const int rsw = rA & 7;
            const short* kbase = &Ks[cur][rA * 64];
            s16x8 kh[4];
#pragma unroll
            for (int c = 0; c < 4; ++c)
                kh[c] = *reinterpret_cast<const s16x8*>(kbase + ((c * 2 + hi) ^ rsw) * 8);
            f32x16 acc = {0.f,0.f,0.f,0.f,0.f,0.f,0.f,0.f,0.f,0.f,0.f,0.f,0.f,0.f,0.f,0.f};
#pragma unroll
            for (int c = 0; c < 4; ++c)  // Kh . Qh
                acc = __builtin_amdgcn_mfma_f32_32x32x16_bf16(kh[c], qf[c], acc, 0, 0, 0);
#pragma unroll
            for (int c = 0; c < 4; ++c)  // Kh . Ql
                acc = __builtin_amdgcn_mfma_f32_32x32x16_bf16(kh[c], qf[c + 4], acc, 0, 0, 0);

            // wave-uniform far test for this 32-kv subtile vs this wave's 32 q-rows
            const int kvT0 = kv0 + T * 32;
            const int dmax = kvT0 + 31 - qw0;   // max delta over (lane, elem)
            const int dmin = kvT0 - qw0 - 31;   // min delta
            const bool faru = (dmax <= -91) || (dmin >= 91);
            const float bunif = (dmax <= -91) ? bneg : bpos;

            auto softpv = [&](bool far) {
#pragma unroll
                for (int t2 = 0; t2 < 2; ++t2) {
                    u32 pk[4];
#pragma unroll
                    for (int i = 0; i < 4; ++i) {
                        const int ii = t2 * 4 + i;
                        const int pstart = ((ii & 1) * 2) + ((ii >> 1) * 8);
                        float b0, b1;
                        if (far) {
                            b0 = bunif; b1 = bunif;
                        } else {
                            const int kvg = kv0 + T * 32 + pstart + 4 * hi;  // even
                            const int i0 = kvg - qL + 255;
                            const short* bp = (i0 & 1) ? (Bsh1 + (i0 - 1)) : (Bsh0 + i0);
                            const u32 pr2 = *reinterpret_cast<const u32*>(bp);  // 4B-aligned
                            b0 = bf2f((short)(pr2 & 0xffff));
                            b1 = bf2f((short)(pr2 >> 16));
                        }
                        const int r0 = t2 * 8 + i * 2;
                        const float e0 = fexp2(acc[r0] + b0);
                        const float e1 = fexp2(acc[r0 + 1] + b1);
                        psum += e0 + e1;
                        pk[i] = pack2(e0, e1);
                    }
                    pl32swap(pk[0], pk[2]);
                    pl32swap(pk[1], pk[3]);
                    u32x4 pv4 = {pk[0], pk[1], pk[2], pk[3]};
                    s16x8 pfrag = __builtin_bit_cast(s16x8, pv4);
                    const int tg = T * 2 + t2;
#pragma unroll
                    for (int dt = 0; dt < 2; ++dt) {
                        const int d = dt * 32 + l31;
                        s16x8 vf = *reinterpret_cast<const s16x8*>(
                            &Vs[cur][d * 64 + ((tg * 2 + hi) ^ (d & 7)) * 8]);
                        accO[dt] = __builtin_amdgcn_mfma_f32_32x32x16_bf16(pfrag, vf, accO[dt], 0, 0, 0);
                    }
                }
            };
            if (faru) softpv(true);   // wave-uniform branch: skips all bias LDS reads
            else      softpv(false);
        }
        __syncthreads();
    }

    psum += __shfl_xor(psum, 32);

    const int bb = bh >> 4;
#pragma unroll
    for (int r = 0; r < 16; ++r) {
        const int qloc = (r & 3) + 8 * (r >> 2) + 4 * hi;
        const float inv = frcp(__shfl(psum, qloc));
        const size_t rowbase = ((size_t)(bb * 2048 + qw0 + qloc)) * 1024 + h * 64;
#pragma unroll
        for (int dt = 0; dt < 2; ++dt)
            attnb[rowbase + dt * 32 + l31] = f2bf(accO[dt][r] * inv);
    }
}

extern "C" void kernel_launch(void* const* d_in, const int* in_sizes, int n_in,
                              void* d_out, int out_size, void* d_ws, size_t ws_size,
                              hipStream_t stream) {
    const float* X = (const float*)d_in[0];
    const float* Wq = (const float*)d_in[1];
    const float* Wk = (const float*)d_in[2];
    const float* Wv = (const float*)d_in[3];
    const float* Wo = (const float*)d_in[4];
    const float* RB = (const float*)d_in[5];

    char* ws = (char*)d_ws;
    size_t off = 0;
    auto alloc = [&](size_t bytes) {
        void* p = ws + off;
        off += (bytes + 255) & ~(size_t)255;
        return p;
    };
    short* X2 = (short*)alloc((size_t)8192 * 1024 * 2);      // X hi only
    short* WT2 = (short*)alloc((size_t)3072 * 2048 * 2);
    short* q2 = (short*)alloc((size_t)64 * 2048 * 128 * 2);
    short* k2 = (short*)alloc((size_t)64 * 2048 * 64 * 2);   // hi-only, 64-wide
    short* vt = (short*)alloc((size_t)64 * 64 * 2048 * 2);
    short* attn = (short*)alloc((size_t)8192 * 1024 * 2);
    short* WoT = (short*)alloc((size_t)1024 * 1024 * 2);
    short* btab = (short*)alloc((size_t)16 * 4096 * 2);

    // merged prep: xconv (8192 blocks) + wconv (4096) + bias (256)
    prep_kernel<<<12544, 256, 0, stream>>>(X, Wq, Wk, Wv, Wo, RB, X2, WT2, WoT, btab);
    // Fused QKV projection (2D grid, default mapping -- r17 revert), BK=64:
    // Q 32 iters (2-term), K 16 iters (1-term), V 16 iters.
    gemm_bt<1><<<dim3(64, 24), 256, 0, stream>>>(X2, WT2, 3072, 1024, 2048, 1024, 2048,
                                                 nullptr, 0, q2, k2, vt);
    flash_kernel<<<512, 512, 0, stream>>>(q2, k2, vt, btab, attn);
    // Output projection (single bf16), K=1024 -> 16 iters
    gemm_bt<0><<<dim3(64, 8), 256, 0, stream>>>(attn, WoT, 1024, 1024, 1024, 1 << 30, 1 << 30,
                                                (float*)d_out, 1024, nullptr, nullptr, nullptr);
}